// Round 5
// baseline (230.526 us; speedup 1.0000x reference)
//
#include <hip/hip_runtime.h>
#include <hip/hip_bf16.h>

typedef __bf16 bf16;
typedef __attribute__((ext_vector_type(8))) __bf16 bf16x8;
typedef __attribute__((ext_vector_type(4))) __bf16 bf16x4;
typedef __attribute__((ext_vector_type(4))) float f32x4;

#define MFMA16(a, b, c) __builtin_amdgcn_mfma_f32_16x16x32_bf16((a), (b), (c), 0, 0, 0)

// async global->LDS, 16B per lane; LDS dest must be wave-uniform base + lane*16
#define GLOAD_LDS16(gp, lp)                                                              \
  __builtin_amdgcn_global_load_lds(                                                      \
      (const __attribute__((address_space(1))) unsigned int*)(gp),                       \
      (__attribute__((address_space(3))) unsigned int*)(lp), 16, 0, 0)

#define BAR()   __builtin_amdgcn_s_barrier()
#define LGKM0() asm volatile("s_waitcnt lgkmcnt(0)" ::: "memory")
#define VMC(n)  asm volatile("s_waitcnt vmcnt(" #n ")" ::: "memory")

// ---------------------------------------------------------------------------
// fused f32 -> bf16 conversion for x + all four weights (one dispatch)
// ---------------------------------------------------------------------------
__global__ __launch_bounds__(256) void cvt_all(const float* __restrict__ x,
                                               const float* __restrict__ wq,
                                               const float* __restrict__ wk,
                                               const float* __restrict__ wv,
                                               const float* __restrict__ wo,
                                               bf16* __restrict__ xb,
                                               bf16* __restrict__ wqkv,
                                               bf16* __restrict__ wob) {
  constexpr int NXC = 8388608 / 8;   // x chunks of 8 elems
  constexpr int NWC = 1048576 / 8;   // per-weight chunks
  constexpr int TOT = NXC + 4 * NWC;
  for (int c = blockIdx.x * 256 + threadIdx.x; c < TOT; c += gridDim.x * 256) {
    const float* src; bf16* dst; int idx;
    if (c < NXC) { src = x; dst = xb; idx = c; }
    else {
      int c2 = c - NXC; int wsel = c2 >> 17; idx = c2 & (NWC - 1);
      src = wsel == 0 ? wq : wsel == 1 ? wk : wsel == 2 ? wv : wo;
      dst = wsel < 3 ? wqkv + (size_t)wsel * 1048576 : wob;
    }
    float4 v0 = reinterpret_cast<const float4*>(src)[idx * 2];
    float4 v1 = reinterpret_cast<const float4*>(src)[idx * 2 + 1];
    bf16x8 o;
    o[0] = (bf16)v0.x; o[1] = (bf16)v0.y; o[2] = (bf16)v0.z; o[3] = (bf16)v0.w;
    o[4] = (bf16)v1.x; o[5] = (bf16)v1.y; o[6] = (bf16)v1.z; o[7] = (bf16)v1.w;
    reinterpret_cast<bf16x8*>(dst)[idx] = o;
  }
}

// ---------------------------------------------------------------------------
// 8-phase 256x256 NT GEMM for the QKV projection (T2+T3+T4+T5).
// M=8192, N=3072, K=1024. 512 threads = 8 waves (2M x 4N), wave tile 128x64.
// LDS: even/odd K-tile buffers, each A[256][64]+B[256][64] bf16, 128 KiB total.
// Halves: A by row-bit6 (quadrant mh), B by row-bit5 (quadrant nh).
// Issue schedule / vmcnt(6)@ph4,8 derived per the 8-phase template.
// Epilogue: col<2048 -> QK[m*2048+col] bf16; col>=2048 -> VT[b,h,d,s] bf16.
// ---------------------------------------------------------------------------
#define MMA_Q(AF, BF, MH, NH)                                                       \
  _Pragma("unroll") for (int mi = 0; mi < 4; ++mi)                                  \
  _Pragma("unroll") for (int ni = 0; ni < 2; ++ni)                                  \
  _Pragma("unroll") for (int ks = 0; ks < 2; ++ks)                                  \
      acc[(MH) * 4 + mi][(NH) * 2 + ni] =                                           \
          MFMA16((AF)[mi][ks], (BF)[ni][ks], acc[(MH) * 4 + mi][(NH) * 2 + ni]);

__global__ __launch_bounds__(512, 2) void gemm8_qkv(const bf16* __restrict__ A,
                                                    const bf16* __restrict__ B,
                                                    bf16* __restrict__ QK,
                                                    bf16* __restrict__ VT) {
  constexpr int K = 1024;
  __shared__ bf16 As[2][256 * 64];   // 2 x 32 KiB
  __shared__ bf16 Bs[2][256 * 64];   // 2 x 32 KiB
  const int tid = threadIdx.x, lane = tid & 63, w = tid >> 6;
  const int l15 = lane & 15, l16 = lane >> 4;
  const int wr = w >> 2, wc = w & 3;
  // XCD-bijective swizzle over 384 blocks (384 % 8 == 0)
  const int lin = blockIdx.x;
  const int swz = (lin & 7) * 48 + (lin >> 3);
  const int bm0 = (swz & 31) * 256, bn0 = (swz >> 5) * 256;

  // staging: one half-tile = 128 rows x 64 cols; 2 x 16B chunks per thread.
  // LDS dest linear (wave-uniform + lane*16); source granule pre-swizzled g^(r&7).
  auto stA = [&](int buf, int t, int h) {
#pragma unroll
    for (int i = 0; i < 2; ++i) {
      const int c = tid + 512 * i, rh = c >> 3;
      const int r = (rh & 63) | (h << 6) | ((rh >> 6) << 7);   // rows with bit6==h
      const int g = (c & 7) ^ (r & 7);
      GLOAD_LDS16(&A[(size_t)(bm0 + r) * K + t * 64 + g * 8], &As[buf][r * 64 + (c & 7) * 8]);
    }
  };
  auto stB = [&](int buf, int t, int h) {
#pragma unroll
    for (int i = 0; i < 2; ++i) {
      const int c = tid + 512 * i, rh = c >> 3;
      const int r = (rh & 31) | (h << 5) | ((rh >> 5) << 6);   // rows with bit5==h
      const int g = (c & 7) ^ (r & 7);
      GLOAD_LDS16(&B[(size_t)(bn0 + r) * K + t * 64 + g * 8], &Bs[buf][r * 64 + (c & 7) * 8]);
    }
  };
  // fragment loads (swizzled read side; row&7 == l15&7 at all frag rows)
  auto ldA = [&](int buf, int mh, bf16x8 (&af)[4][2]) {
#pragma unroll
    for (int mi = 0; mi < 4; ++mi)
#pragma unroll
      for (int ks = 0; ks < 2; ++ks)
        af[mi][ks] = *reinterpret_cast<const bf16x8*>(
            &As[buf][(wr * 128 + mh * 64 + mi * 16 + l15) * 64 +
                     (((ks * 4 + l16) ^ (l15 & 7)) * 8)]);
  };
  auto ldB = [&](int buf, int nh, bf16x8 (&bfr)[2][2]) {
#pragma unroll
    for (int ni = 0; ni < 2; ++ni)
#pragma unroll
      for (int ks = 0; ks < 2; ++ks)
        bfr[ni][ks] = *reinterpret_cast<const bf16x8*>(
            &Bs[buf][(wc * 64 + nh * 32 + ni * 16 + l15) * 64 +
                     (((ks * 4 + l16) ^ (l15 & 7)) * 8)]);
  };

  f32x4 acc[8][4] = {};
  bf16x8 af[4][2], b0[2][2], b1[2][2];

  // prologue: tile0 complete (A0,B0,B1,A1 oldest-first) + tile1 {A0,B0,B1}
  stA(0, 0, 0); stB(0, 0, 0); stB(0, 0, 1); stA(0, 0, 1);
  stA(1, 1, 0); stB(1, 1, 0); stB(1, 1, 1);
  VMC(6);                                   // tile0 fully landed
  BAR();

#pragma unroll 1
  for (int it = 0; it < K / 128; ++it) {
    const int t0 = it * 2;
    const bool last = (it == K / 128 - 1);
    // phase 1: quad(0,0) buf0            issue: tile(t0+1).A1
    ldA(0, 0, af); ldB(0, 0, b0);
    stA(1, t0 + 1, 1);
    BAR(); LGKM0();
    __builtin_amdgcn_s_setprio(1); MMA_Q(af, b0, 0, 0); __builtin_amdgcn_s_setprio(0);
    BAR();
    // phase 2: quad(0,1)                 issue: tile(t0+2).A0
    ldB(0, 1, b1);
    if (!last) stA(0, t0 + 2, 0);
    BAR(); LGKM0();
    __builtin_amdgcn_s_setprio(1); MMA_Q(af, b1, 0, 1); __builtin_amdgcn_s_setprio(0);
    BAR();
    // phase 3: quad(1,1)                 issue: tile(t0+2).B0
    ldA(0, 1, af);
    if (!last) stB(0, t0 + 2, 0);
    BAR(); LGKM0();
    __builtin_amdgcn_s_setprio(1); MMA_Q(af, b1, 1, 1); __builtin_amdgcn_s_setprio(0);
    BAR();
    // phase 4: quad(1,0)                 issue: tile(t0+2).B1   gate buf1
    if (!last) stB(0, t0 + 2, 1);
    BAR(); LGKM0();
    __builtin_amdgcn_s_setprio(1); MMA_Q(af, b0, 1, 0); __builtin_amdgcn_s_setprio(0);
    if (last) { VMC(0); } else { VMC(6); }
    BAR();
    // phase 5: quad(0,0) buf1            issue: tile(t0+2).A1
    ldA(1, 0, af); ldB(1, 0, b0);
    if (!last) stA(0, t0 + 2, 1);
    BAR(); LGKM0();
    __builtin_amdgcn_s_setprio(1); MMA_Q(af, b0, 0, 0); __builtin_amdgcn_s_setprio(0);
    BAR();
    // phase 6: quad(0,1)                 issue: tile(t0+3).A0
    ldB(1, 1, b1);
    if (!last) stA(1, t0 + 3, 0);
    BAR(); LGKM0();
    __builtin_amdgcn_s_setprio(1); MMA_Q(af, b1, 0, 1); __builtin_amdgcn_s_setprio(0);
    BAR();
    // phase 7: quad(1,1)                 issue: tile(t0+3).B0
    ldA(1, 1, af);
    if (!last) stB(1, t0 + 3, 0);
    BAR(); LGKM0();
    __builtin_amdgcn_s_setprio(1); MMA_Q(af, b1, 1, 1); __builtin_amdgcn_s_setprio(0);
    BAR();
    // phase 8: quad(1,0)                 issue: tile(t0+3).B1   gate buf0
    if (!last) stB(1, t0 + 3, 1);
    BAR(); LGKM0();
    __builtin_amdgcn_s_setprio(1); MMA_Q(af, b0, 1, 0); __builtin_amdgcn_s_setprio(0);
    if (!last) VMC(6);
    BAR();
  }

  // epilogue: row = bm0 + wr*128 + mi8*16 + l16*4 + r, col = bn0 + wc*64 + ni4*16 + l15
#pragma unroll
  for (int mi = 0; mi < 8; ++mi)
#pragma unroll
    for (int ni = 0; ni < 4; ++ni)
#pragma unroll
      for (int r = 0; r < 4; ++r) {
        const int row = bm0 + wr * 128 + mi * 16 + l16 * 4 + r;
        const int col = bn0 + wc * 64 + ni * 16 + l15;
        const float v = acc[mi][ni][r];
        if (col < 2048)
          QK[(size_t)row * 2048 + col] = (bf16)v;
        else
          VT[((size_t)(row >> 11) * 1024 + (col - 2048)) * 2048 + (row & 2047)] = (bf16)v;
      }
}

// ---------------------------------------------------------------------------
// 128x128 NT GEMM (m97 structure) — used for the output projection (f32 out)
// ---------------------------------------------------------------------------
constexpr int BM = 128, BN = 128, BK = 64;

__global__ __launch_bounds__(256) void gemm_nt_f32(const bf16* __restrict__ A,
                                                   const bf16* __restrict__ B,
                                                   float* __restrict__ C,
                                                   int N, int K) {
  __shared__ bf16 As[BM * BK];
  __shared__ bf16 Bs[BN * BK];
  const int tid = threadIdx.x;
  const int lane = tid & 63;
  const int w = tid >> 6;
  const int wm = (w & 1) * 64, wn = (w >> 1) * 64;
  const int l15 = lane & 15, l16 = lane >> 4;
  const int bm0 = blockIdx.x * BM, bn0 = blockIdx.y * BN;
  f32x4 acc[4][4] = {};
  for (int k0 = 0; k0 < K; k0 += BK) {
#pragma unroll
    for (int i = 0; i < 4; ++i) {
      const int c = tid + 256 * i;
      const int row = c >> 3, col = (c & 7) * 8;
      GLOAD_LDS16(&A[(size_t)(bm0 + row) * K + k0 + col], &As[c * 8]);
      GLOAD_LDS16(&B[(size_t)(bn0 + row) * K + k0 + col], &Bs[c * 8]);
    }
    __syncthreads();
#pragma unroll
    for (int kk = 0; kk < 2; ++kk) {
      bf16x8 afr[4], bfr[4];
#pragma unroll
      for (int i = 0; i < 4; ++i)
        afr[i] = *reinterpret_cast<bf16x8*>(&As[(wm + i * 16 + l15) * BK + kk * 32 + l16 * 8]);
#pragma unroll
      for (int i = 0; i < 4; ++i)
        bfr[i] = *reinterpret_cast<bf16x8*>(&Bs[(wn + i * 16 + l15) * BK + kk * 32 + l16 * 8]);
#pragma unroll
      for (int mi = 0; mi < 4; ++mi)
#pragma unroll
        for (int ni = 0; ni < 4; ++ni)
          acc[mi][ni] = MFMA16(afr[mi], bfr[ni], acc[mi][ni]);
    }
    __syncthreads();
  }
#pragma unroll
  for (int mi = 0; mi < 4; ++mi)
#pragma unroll
    for (int ni = 0; ni < 4; ++ni)
#pragma unroll
      for (int r = 0; r < 4; ++r) {
        size_t row = bm0 + wm + mi * 16 + l16 * 4 + r;
        size_t col = bn0 + wn + ni * 16 + l15;
        C[row * N + col] = acc[mi][ni][r];
      }
}

// ---------------------------------------------------------------------------
// Causal attention, no max subtraction (faithful to reference softmax):
//   P = exp(QK^T / 8) (0 above diagonal), O = (P @ V) / (rowsum(P) + 1e-10)
// QK packed [B,S,2048]: Q cols h*64, K cols 1024+h*64. VT [b,h,d(64),s(2048)].
// ---------------------------------------------------------------------------
constexpr int S_ = 2048, H_ = 16, LDQK = 2048;

__global__ __launch_bounds__(256) void attn_kernel(const bf16* __restrict__ QK,
                                                   const bf16* __restrict__ VT,
                                                   bf16* __restrict__ AO) {
  __shared__ bf16 Ks[64 * 64];         // K tile  [kv][hd]  swizzled   8 KB
  __shared__ bf16 Vs[64 * 64];         // V^T tile [hd][kv] swizzled   8 KB
  __shared__ bf16 Ps[4][32 * 64];      // per-wave P [q][kv] swizzled 16 KB
  const int tid = threadIdx.x, lane = tid & 63, w = tid >> 6;
  const int l15 = lane & 15, l16 = lane >> 4;
  const int bh = blockIdx.x, b = bh >> 4, h = bh & (H_ - 1);
  const int qy = blockIdx.y;
  const int qt = qy ^ (((qy >> 2) & 1) * 3);   // load-balance remap (bijective)
  const int q0 = qt * 128;
  const size_t qoff = (size_t)b * S_ * LDQK + h * 64;
  const size_t koff = qoff + 1024;
  const size_t voff = (size_t)bh * 64 * LDQK;  // VT row stride 2048
  const int qrow = q0 + w * 32;
  const int tmax = (qrow + 31) >> 6;           // this wave's diagonal tile

  bf16x8 qf[2][2];
#pragma unroll
  for (int mi = 0; mi < 2; ++mi)
#pragma unroll
    for (int kk = 0; kk < 2; ++kk)
      qf[mi][kk] = *reinterpret_cast<const bf16x8*>(
          &QK[qoff + (size_t)(qrow + mi * 16 + l15) * LDQK + kk * 32 + l16 * 8]);

  f32x4 o[2][4] = {};
  float rs[2][4] = {};
  const int ntiles = 2 * qt + 2;

  for (int t = 0; t < ntiles; ++t) {
    const int kv0 = t * 64;
#pragma unroll
    for (int i = 0; i < 2; ++i) {
      const int c = tid + 256 * i;
      const int row = c >> 3, gs = (c & 7) ^ (row & 7);
      GLOAD_LDS16(&QK[koff + (size_t)(kv0 + row) * LDQK + gs * 8], &Ks[c * 8]);
      GLOAD_LDS16(&VT[voff + (size_t)row * LDQK + kv0 + gs * 8], &Vs[c * 8]);
    }
    __syncthreads();

    if (t <= tmax) {
      f32x4 sc[2][4] = {};
      bf16x8 kf[4][2];
#pragma unroll
      for (int ni = 0; ni < 4; ++ni)
#pragma unroll
        for (int kk = 0; kk < 2; ++kk)
          kf[ni][kk] = *reinterpret_cast<bf16x8*>(
              &Ks[(ni * 16 + l15) * 64 + (((kk * 4 + l16) ^ (l15 & 7)) * 8)]);
#pragma unroll
      for (int mi = 0; mi < 2; ++mi)
#pragma unroll
        for (int ni = 0; ni < 4; ++ni)
#pragma unroll
          for (int kk = 0; kk < 2; ++kk)
            sc[mi][ni] = MFMA16(qf[mi][kk], kf[ni][kk], sc[mi][ni]);

      if (t == tmax) {
#pragma unroll
        for (int mi = 0; mi < 2; ++mi)
#pragma unroll
          for (int ni = 0; ni < 4; ++ni)
#pragma unroll
            for (int r = 0; r < 4; ++r) {
              const int lrow = mi * 16 + l16 * 4 + r;
              const int lcol = ni * 16 + l15;
              float p = (kv0 + lcol <= qrow + lrow) ? __expf(sc[mi][ni][r] * 0.125f) : 0.0f;
              rs[mi][r] += p;
              Ps[w][lrow * 64 + (lcol ^ ((lrow & 7) << 3))] = (bf16)p;
            }
      } else {
#pragma unroll
        for (int mi = 0; mi < 2; ++mi)
#pragma unroll
          for (int ni = 0; ni < 4; ++ni)
#pragma unroll
            for (int r = 0; r < 4; ++r) {
              const int lrow = mi * 16 + l16 * 4 + r;
              const int lcol = ni * 16 + l15;
              float p = __expf(sc[mi][ni][r] * 0.125f);
              rs[mi][r] += p;
              Ps[w][lrow * 64 + (lcol ^ ((lrow & 7) << 3))] = (bf16)p;
            }
      }

      bf16x8 pf[2][2], vf[4][2];
#pragma unroll
      for (int mi = 0; mi < 2; ++mi)
#pragma unroll
        for (int kk = 0; kk < 2; ++kk)
          pf[mi][kk] = *reinterpret_cast<bf16x8*>(
              &Ps[w][(mi * 16 + l15) * 64 + (((kk * 4 + l16) ^ (l15 & 7)) * 8)]);
#pragma unroll
      for (int ni = 0; ni < 4; ++ni)
#pragma unroll
        for (int kk = 0; kk < 2; ++kk)
          vf[ni][kk] = *reinterpret_cast<bf16x8*>(
              &Vs[(ni * 16 + l15) * 64 + (((kk * 4 + l16) ^ (l15 & 7)) * 8)]);
#pragma unroll
      for (int mi = 0; mi < 2; ++mi)
#pragma unroll
        for (int ni = 0; ni < 4; ++ni)
#pragma unroll
          for (int kk = 0; kk < 2; ++kk)
            o[mi][ni] = MFMA16(pf[mi][kk], vf[ni][kk], o[mi][ni]);
    }
    __syncthreads();
  }

#pragma unroll
  for (int mi = 0; mi < 2; ++mi)
#pragma unroll
    for (int r = 0; r < 4; ++r) {
      float v = rs[mi][r];
      v += __shfl_xor(v, 1);
      v += __shfl_xor(v, 2);
      v += __shfl_xor(v, 4);
      v += __shfl_xor(v, 8);
      rs[mi][r] = v + 1e-10f;
    }

  const size_t aoff = (size_t)b * S_ * 1024 + h * 64;
#pragma unroll
  for (int mi = 0; mi < 2; ++mi)
#pragma unroll
    for (int ni = 0; ni < 4; ++ni)
#pragma unroll
      for (int r = 0; r < 4; ++r) {
        int row = qrow + mi * 16 + l16 * 4 + r;
        AO[aoff + (size_t)row * 1024 + ni * 16 + l15] = (bf16)(o[mi][ni][r] / rs[mi][r]);
      }
}

// ---------------------------------------------------------------------------
extern "C" void kernel_launch(void* const* d_in, const int* in_sizes, int n_in,
                              void* d_out, int out_size, void* d_ws, size_t ws_size,
                              hipStream_t stream) {
  const float* x  = (const float*)d_in[0];
  // d_in[1] = mask: exactly causal additive -1e9; handled analytically, unused.
  const float* Wq = (const float*)d_in[2];
  const float* Wk = (const float*)d_in[3];
  const float* Wv = (const float*)d_in[4];
  const float* Wo = (const float*)d_in[5];

  constexpr int B = 4, S = 2048, D = 1024;
  constexpr size_t nx = (size_t)B * S * D;       // 8,388,608
  constexpr size_t nw = (size_t)D * D;           // 1,048,576

  char* ws = (char*)d_ws;
  bf16* xb    = (bf16*)ws;                   // x bf16                (16.78 MB)
  bf16* Wqkvb = xb + nx;                     // packed [3072][1024]   ( 6.29 MB)
  bf16* Wob   = Wqkvb + 3 * nw;              // Wo bf16               ( 2.10 MB)
  bf16* QKb   = Wob + nw;                    // QK [B,S,2048]         (33.55 MB)
  bf16* VTb   = QKb + (size_t)B * S * 2048;  // V^T [b,h,64,2048]     (16.78 MB)
  bf16* AOb   = VTb + nx;                    // attn out [B,S,D]      (16.78 MB)

  cvt_all<<<2048, 256, 0, stream>>>(x, Wq, Wk, Wv, Wo, xb, Wqkvb, Wob);

  // fused QKV projection, 8-phase 256^2 template; V third written transposed
  gemm8_qkv<<<384, 512, 0, stream>>>(xb, Wqkvb, QKb, VTb);

  attn_kernel<<<dim3(B * H_, S / 128), 256, 0, stream>>>(QKb, VTb, AOb);

  // output projection -> f32 d_out
  gemm_nt_f32<<<dim3((B * S) / BM, D / BN), 256, 0, stream>>>(AOb, Wob, (float*)d_out, D, D);
}

// Round 6
// 217.664 us; speedup vs baseline: 1.0591x; 1.0591x over previous
//
#include <hip/hip_runtime.h>
#include <hip/hip_bf16.h>

typedef __bf16 bf16;
typedef __attribute__((ext_vector_type(8))) __bf16 bf16x8;
typedef __attribute__((ext_vector_type(4))) float f32x4;

#define MFMA16(a, b, c) __builtin_amdgcn_mfma_f32_16x16x32_bf16((a), (b), (c), 0, 0, 0)

// async global->LDS, 16B per lane; LDS dest must be wave-uniform base + lane*16
#define GLOAD_LDS16(gp, lp)                                                              \
  __builtin_amdgcn_global_load_lds(                                                      \
      (const __attribute__((address_space(1))) unsigned int*)(gp),                       \
      (__attribute__((address_space(3))) unsigned int*)(lp), 16, 0, 0)

#define BAR()  __builtin_amdgcn_s_barrier()
#define VMC0() asm volatile("s_waitcnt vmcnt(0)" ::: "memory")

// ---------------------------------------------------------------------------
// fused f32 -> bf16 conversion for x + all four weights (one dispatch)
// ---------------------------------------------------------------------------
__global__ __launch_bounds__(256) void cvt_all(const float* __restrict__ x,
                                               const float* __restrict__ wq,
                                               const float* __restrict__ wk,
                                               const float* __restrict__ wv,
                                               const float* __restrict__ wo,
                                               bf16* __restrict__ xb,
                                               bf16* __restrict__ wqkv,
                                               bf16* __restrict__ wob) {
  constexpr int NXC = 8388608 / 8;   // x chunks of 8 elems
  constexpr int NWC = 1048576 / 8;   // per-weight chunks
  constexpr int TOT = NXC + 4 * NWC;
  for (int c = blockIdx.x * 256 + threadIdx.x; c < TOT; c += gridDim.x * 256) {
    const float* src; bf16* dst; int idx;
    if (c < NXC) { src = x; dst = xb; idx = c; }
    else {
      int c2 = c - NXC; int wsel = c2 >> 17; idx = c2 & (NWC - 1);
      src = wsel == 0 ? wq : wsel == 1 ? wk : wsel == 2 ? wv : wo;
      dst = wsel < 3 ? wqkv + (size_t)wsel * 1048576 : wob;
    }
    float4 v0 = reinterpret_cast<const float4*>(src)[idx * 2];
    float4 v1 = reinterpret_cast<const float4*>(src)[idx * 2 + 1];
    bf16x8 o;
    o[0] = (bf16)v0.x; o[1] = (bf16)v0.y; o[2] = (bf16)v0.z; o[3] = (bf16)v0.w;
    o[4] = (bf16)v1.x; o[5] = (bf16)v1.y; o[6] = (bf16)v1.z; o[7] = (bf16)v1.w;
    reinterpret_cast<bf16x8*>(dst)[idx] = o;
  }
}

// ---------------------------------------------------------------------------
// NT GEMM (m97 structure, proven R3): C[m,n] = sum_k A[m,k]*B[n,k]
// 128x128 tile, BK=64, 4 waves, linear LDS + global_load_lds dwordx4.
// 5 blocks/CU co-residency hides the per-tile stage drain (m114 overlap).
// MODE 0: f32 out at [m*N+n].
// MODE 2 (QKV): n<2048 -> bf16 QK[m*2048+n]; n>=2048 -> bf16 VT transposed,
//   VT[((m>>11)*1024 + (n-2048))*2048 + (m&2047)]   (layout [b,h,d,s])
// ---------------------------------------------------------------------------
constexpr int BM = 128, BN = 128, BK = 64;

template <int MODE>
__global__ __launch_bounds__(256) void gemm_nt(const bf16* __restrict__ A,
                                               const bf16* __restrict__ B,
                                               void* __restrict__ Cv,
                                               void* __restrict__ Cv2,
                                               int N, int K) {
  __shared__ bf16 As[BM * BK];   // 16 KB, linear (gload_lds requires linear dest)
  __shared__ bf16 Bs[BN * BK];   // 16 KB
  const int tid = threadIdx.x;
  const int lane = tid & 63;
  const int w = tid >> 6;
  const int wm = (w & 1) * 64, wn = (w >> 1) * 64;
  const int l15 = lane & 15, l16 = lane >> 4;
  const int bm0 = blockIdx.x * BM, bn0 = blockIdx.y * BN;
  f32x4 acc[4][4] = {};
  for (int k0 = 0; k0 < K; k0 += BK) {
#pragma unroll
    for (int i = 0; i < 4; ++i) {
      const int c = tid + 256 * i;          // 16B chunk id; lane-consecutive per wave
      const int row = c >> 3, col = (c & 7) * 8;
      GLOAD_LDS16(&A[(size_t)(bm0 + row) * K + k0 + col], &As[c * 8]);
      GLOAD_LDS16(&B[(size_t)(bn0 + row) * K + k0 + col], &Bs[c * 8]);
    }
    __syncthreads();                         // compiler drains vmcnt before barrier
#pragma unroll
    for (int kk = 0; kk < 2; ++kk) {
      bf16x8 af[4], bfr[4];
#pragma unroll
      for (int i = 0; i < 4; ++i)
        af[i] = *reinterpret_cast<bf16x8*>(&As[(wm + i * 16 + l15) * BK + kk * 32 + l16 * 8]);
#pragma unroll
      for (int i = 0; i < 4; ++i)
        bfr[i] = *reinterpret_cast<bf16x8*>(&Bs[(wn + i * 16 + l15) * BK + kk * 32 + l16 * 8]);
#pragma unroll
      for (int mi = 0; mi < 4; ++mi)
#pragma unroll
        for (int ni = 0; ni < 4; ++ni)
          acc[mi][ni] = MFMA16(af[mi], bfr[ni], acc[mi][ni]);
    }
    __syncthreads();
  }
  // C/D frag layout: col = lane&15, row = (lane>>4)*4 + reg
#pragma unroll
  for (int mi = 0; mi < 4; ++mi)
#pragma unroll
    for (int ni = 0; ni < 4; ++ni)
#pragma unroll
      for (int r = 0; r < 4; ++r) {
        size_t row = bm0 + wm + mi * 16 + l16 * 4 + r;
        size_t col = bn0 + wn + ni * 16 + l15;
        float v = acc[mi][ni][r];
        if constexpr (MODE == 0) {
          reinterpret_cast<float*>(Cv)[row * N + col] = v;
        } else {
          if (col < 2048)
            reinterpret_cast<bf16*>(Cv)[row * 2048 + col] = (bf16)v;
          else
            reinterpret_cast<bf16*>(Cv2)[((row >> 11) * 1024 + (col - 2048)) * 2048 +
                                         (row & 2047)] = (bf16)v;
        }
      }
}

// ---------------------------------------------------------------------------
// Causal attention, no max subtraction (faithful to reference softmax):
//   P = exp(QK^T / 8) (0 above diagonal), O = (P @ V) / (rowsum(P) + 1e-10)
// QK packed [B,S,2048]: Q cols h*64, K cols 1024+h*64. VT [b,h,d(64),s(2048)].
// Pipeline (T3 minimal 2-phase): stage(t+1) issued BEFORE compute(t); K/V in
// double-buffered LDS; ONE vmcnt(0)+barrier per tile -> stage latency hides
// under QK^T+softmax+PV. Race audit: stage(t+1) writes buf[(t+1)&1], whose
// last readers (iter t-1) were certified by the barrier ending t-1; Ps is
// wave-private (no cross-wave reads); so one barrier per tile suffices.
// All LDS XOR-swizzled (granule g ^= row&7), gload_lds with pre-swizzled
// source (rule #21: linear dest + inverse-swizzled source + swizzled read).
// ---------------------------------------------------------------------------
constexpr int S_ = 2048, H_ = 16, LDQK = 2048;

__global__ __launch_bounds__(256) void attn_kernel(const bf16* __restrict__ QK,
                                                   const bf16* __restrict__ VT,
                                                   bf16* __restrict__ AO) {
  __shared__ bf16 Ks[2][64 * 64];      // K tile  [kv][hd]  swizzled, dbuf  16 KB
  __shared__ bf16 Vs[2][64 * 64];      // V^T tile [hd][kv] swizzled, dbuf  16 KB
  __shared__ bf16 Ps[4][32 * 64];      // per-wave P [q][kv] swizzled       16 KB
  const int tid = threadIdx.x, lane = tid & 63, w = tid >> 6;
  const int l15 = lane & 15, l16 = lane >> 4;
  const int bh = blockIdx.x, b = bh >> 4, h = bh & (H_ - 1);
  const int qy = blockIdx.y;
  const int qt = qy ^ (((qy >> 2) & 1) * 3);   // load-balance remap (bijective)
  const int q0 = qt * 128;
  const size_t qoff = (size_t)b * S_ * LDQK + h * 64;
  const size_t koff = qoff + 1024;
  const size_t voff = (size_t)bh * 64 * LDQK;  // VT row stride 2048
  const int qrow = q0 + w * 32;
  const int tmax = (qrow + 31) >> 6;           // this wave's diagonal tile

  // stage K tile and V^T tile for KV-tile t into buffer t&1
  auto stage = [&](int t) {
    const int kv0 = t * 64, bs = t & 1;
#pragma unroll
    for (int i = 0; i < 2; ++i) {
      const int c = tid + 256 * i;
      const int row = c >> 3, gs = (c & 7) ^ (row & 7);
      GLOAD_LDS16(&QK[koff + (size_t)(kv0 + row) * LDQK + gs * 8], &Ks[bs][c * 8]);
      GLOAD_LDS16(&VT[voff + (size_t)row * LDQK + kv0 + gs * 8], &Vs[bs][c * 8]);
    }
  };

  // Q fragments held in registers for the whole kernel
  bf16x8 qf[2][2];
#pragma unroll
  for (int mi = 0; mi < 2; ++mi)
#pragma unroll
    for (int kk = 0; kk < 2; ++kk)
      qf[mi][kk] = *reinterpret_cast<const bf16x8*>(
          &QK[qoff + (size_t)(qrow + mi * 16 + l15) * LDQK + kk * 32 + l16 * 8]);

  f32x4 o[2][4] = {};
  float rs[2][4] = {};
  const int ntiles = 2 * qt + 2;

  stage(0);
  VMC0(); BAR();

  for (int t = 0; t < ntiles; ++t) {
    if (t + 1 < ntiles) stage(t + 1);          // issue-early: hides under compute
    if (t <= tmax) {                           // skip fully-masked tiles
      const int bs = t & 1;
      const int kv0 = t * 64;
      // scores = Q (32x64) @ K^T (64x64), swizzled kf reads
      f32x4 sc[2][4] = {};
      bf16x8 kf[4][2];
#pragma unroll
      for (int ni = 0; ni < 4; ++ni)
#pragma unroll
        for (int kk = 0; kk < 2; ++kk)
          kf[ni][kk] = *reinterpret_cast<bf16x8*>(
              &Ks[bs][(ni * 16 + l15) * 64 + (((kk * 4 + l16) ^ (l15 & 7)) * 8)]);
#pragma unroll
      for (int mi = 0; mi < 2; ++mi)
#pragma unroll
        for (int ni = 0; ni < 4; ++ni)
#pragma unroll
          for (int kk = 0; kk < 2; ++kk)
            sc[mi][ni] = MFMA16(qf[mi][kk], kf[ni][kk], sc[mi][ni]);

      // softmax numerator (no max subtraction, matches reference); mask only
      // on the diagonal tile (wave-uniform branch). P staged swizzled.
      if (t == tmax) {
#pragma unroll
        for (int mi = 0; mi < 2; ++mi)
#pragma unroll
          for (int ni = 0; ni < 4; ++ni)
#pragma unroll
            for (int r = 0; r < 4; ++r) {
              const int lrow = mi * 16 + l16 * 4 + r;
              const int lcol = ni * 16 + l15;
              float p = (kv0 + lcol <= qrow + lrow) ? __expf(sc[mi][ni][r] * 0.125f) : 0.0f;
              rs[mi][r] += p;
              Ps[w][lrow * 64 + (lcol ^ ((lrow & 7) << 3))] = (bf16)p;
            }
      } else {
#pragma unroll
        for (int mi = 0; mi < 2; ++mi)
#pragma unroll
          for (int ni = 0; ni < 4; ++ni)
#pragma unroll
            for (int r = 0; r < 4; ++r) {
              const int lrow = mi * 16 + l16 * 4 + r;
              const int lcol = ni * 16 + l15;
              float p = __expf(sc[mi][ni][r] * 0.125f);
              rs[mi][r] += p;
              Ps[w][lrow * 64 + (lcol ^ ((lrow & 7) << 3))] = (bf16)p;
            }
      }

      // O += P (32x64) @ V (64x64): A = P rows q, B = V^T rows d, swizzled
      bf16x8 pf[2][2], vf[4][2];
#pragma unroll
      for (int mi = 0; mi < 2; ++mi)
#pragma unroll
        for (int kk = 0; kk < 2; ++kk)
          pf[mi][kk] = *reinterpret_cast<bf16x8*>(
              &Ps[w][(mi * 16 + l15) * 64 + (((kk * 4 + l16) ^ (l15 & 7)) * 8)]);
#pragma unroll
      for (int ni = 0; ni < 4; ++ni)
#pragma unroll
        for (int kk = 0; kk < 2; ++kk)
          vf[ni][kk] = *reinterpret_cast<bf16x8*>(
              &Vs[bs][(ni * 16 + l15) * 64 + (((kk * 4 + l16) ^ (l15 & 7)) * 8)]);
#pragma unroll
      for (int mi = 0; mi < 2; ++mi)
#pragma unroll
        for (int ni = 0; ni < 4; ++ni)
#pragma unroll
          for (int kk = 0; kk < 2; ++kk)
            o[mi][ni] = MFMA16(pf[mi][kk], vf[ni][kk], o[mi][ni]);
    }
    VMC0(); BAR();   // t+1's loads landed (issued before compute -> ~free wait)
  }

  // full rowsum: reduce partials across the 16 lanes sharing (lane>>4)
#pragma unroll
  for (int mi = 0; mi < 2; ++mi)
#pragma unroll
    for (int r = 0; r < 4; ++r) {
      float v = rs[mi][r];
      v += __shfl_xor(v, 1);
      v += __shfl_xor(v, 2);
      v += __shfl_xor(v, 4);
      v += __shfl_xor(v, 8);
      rs[mi][r] = v + 1e-10f;
    }

  // normalize + write attention output (bf16, [B,S,1024] layout)
  const size_t aoff = (size_t)b * S_ * 1024 + h * 64;
#pragma unroll
  for (int mi = 0; mi < 2; ++mi)
#pragma unroll
    for (int ni = 0; ni < 4; ++ni)
#pragma unroll
      for (int r = 0; r < 4; ++r) {
        int row = qrow + mi * 16 + l16 * 4 + r;
        AO[aoff + (size_t)row * 1024 + ni * 16 + l15] = (bf16)(o[mi][ni][r] / rs[mi][r]);
      }
}

// ---------------------------------------------------------------------------
extern "C" void kernel_launch(void* const* d_in, const int* in_sizes, int n_in,
                              void* d_out, int out_size, void* d_ws, size_t ws_size,
                              hipStream_t stream) {
  const float* x  = (const float*)d_in[0];
  // d_in[1] = mask: exactly causal additive -1e9; handled analytically, unused.
  const float* Wq = (const float*)d_in[2];
  const float* Wk = (const float*)d_in[3];
  const float* Wv = (const float*)d_in[4];
  const float* Wo = (const float*)d_in[5];

  constexpr int B = 4, S = 2048, D = 1024;
  constexpr size_t nx = (size_t)B * S * D;       // 8,388,608
  constexpr size_t nw = (size_t)D * D;           // 1,048,576

  char* ws = (char*)d_ws;
  bf16* xb    = (bf16*)ws;                   // x bf16                (16.78 MB)
  bf16* Wqkvb = xb + nx;                     // packed [3072][1024]   ( 6.29 MB)
  bf16* Wob   = Wqkvb + 3 * nw;              // Wo bf16               ( 2.10 MB)
  bf16* QKb   = Wob + nw;                    // QK [B,S,2048]         (33.55 MB)
  bf16* VTb   = QKb + (size_t)B * S * 2048;  // V^T [b,h,64,2048]     (16.78 MB)
  bf16* AOb   = VTb + nx;                    // attn out [B,S,D]      (16.78 MB)

  cvt_all<<<2048, 256, 0, stream>>>(x, Wq, Wk, Wv, Wo, xb, Wqkvb, Wob);

  // fused QKV projection: [8192x1024] @ [3072x1024]^T; V third written transposed
  gemm_nt<2><<<dim3((B * S) / BM, (3 * D) / BN), 256, 0, stream>>>(xb, Wqkvb, QKb, VTb,
                                                                   3 * D, D);

  attn_kernel<<<dim3(B * H_, S / 128), 256, 0, stream>>>(QKb, VTb, AOb);

  // output projection -> f32 d_out
  gemm_nt<0><<<dim3((B * S) / BM, D / BN), 256, 0, stream>>>(AOb, Wob, (float*)d_out,
                                                             nullptr, D, D);
}

// Round 7
// 182.461 us; speedup vs baseline: 1.2634x; 1.1929x over previous
//
#include <hip/hip_runtime.h>
#include <hip/hip_bf16.h>

typedef __bf16 bf16;
typedef __attribute__((ext_vector_type(8))) __bf16 bf16x8;
typedef __attribute__((ext_vector_type(4))) float f32x4;

#define MFMA16(a, b, c) __builtin_amdgcn_mfma_f32_16x16x32_bf16((a), (b), (c), 0, 0, 0)

// async global->LDS, 16B per lane; LDS dest must be wave-uniform base + lane*16
#define GLOAD_LDS16(gp, lp)                                                              \
  __builtin_amdgcn_global_load_lds(                                                      \
      (const __attribute__((address_space(1))) unsigned int*)(gp),                       \
      (__attribute__((address_space(3))) unsigned int*)(lp), 16, 0, 0)

#define BAR()   __builtin_amdgcn_s_barrier()
#define LGKM0() asm volatile("s_waitcnt lgkmcnt(0)" ::: "memory")
#define VMC(n)  asm volatile("s_waitcnt vmcnt(" #n ")" ::: "memory")
#define PRIO1() __builtin_amdgcn_s_setprio(1)
#define PRIO0() __builtin_amdgcn_s_setprio(0)

// ---------------------------------------------------------------------------
// fused f32 -> bf16 conversion for x + all four weights (one dispatch)
// ---------------------------------------------------------------------------
__global__ __launch_bounds__(256) void cvt_all(const float* __restrict__ x,
                                               const float* __restrict__ wq,
                                               const float* __restrict__ wk,
                                               const float* __restrict__ wv,
                                               const float* __restrict__ wo,
                                               bf16* __restrict__ xb,
                                               bf16* __restrict__ wqkv,
                                               bf16* __restrict__ wob) {
  constexpr int NXC = 8388608 / 8;   // x chunks of 8 elems
  constexpr int NWC = 1048576 / 8;   // per-weight chunks
  constexpr int TOT = NXC + 4 * NWC;
  for (int c = blockIdx.x * 256 + threadIdx.x; c < TOT; c += gridDim.x * 256) {
    const float* src; bf16* dst; int idx;
    if (c < NXC) { src = x; dst = xb; idx = c; }
    else {
      int c2 = c - NXC; int wsel = c2 >> 17; idx = c2 & (NWC - 1);
      src = wsel == 0 ? wq : wsel == 1 ? wk : wsel == 2 ? wv : wo;
      dst = wsel < 3 ? wqkv + (size_t)wsel * 1048576 : wob;
    }
    float4 v0 = reinterpret_cast<const float4*>(src)[idx * 2];
    float4 v1 = reinterpret_cast<const float4*>(src)[idx * 2 + 1];
    bf16x8 o;
    o[0] = (bf16)v0.x; o[1] = (bf16)v0.y; o[2] = (bf16)v0.z; o[3] = (bf16)v0.w;
    o[4] = (bf16)v1.x; o[5] = (bf16)v1.y; o[6] = (bf16)v1.z; o[7] = (bf16)v1.w;
    reinterpret_cast<bf16x8*>(dst)[idx] = o;
  }
}

// ---------------------------------------------------------------------------
// 8-phase NT GEMM, tile 128(M)x256(N), BK=64, K=1024 fixed. 512 thr = 8 waves
// (2M x 4N), wave-tile 64x64, quad 32x32 (8 MFMA/phase). Double-buffered LDS
// (96 KiB). Schedule: phases 1-4 compute buf0 (tile t0), 5-8 buf1 (t0+1).
// buf0's last ds_read is ph3 -> ALL 6 stage-calls for tile t0+2 issue at ph4
// (post-ph3-barrier => no read/write race); mirror at ph8 for t0+3 -> buf1.
// Gates: vmcnt(6) at ph4/ph8 leaves exactly the 6 just-issued calls
// outstanding => previous tile certified landed (T4 counted-vmcnt).
// T2 XOR involution: LDS linear dest, source granule pre-swizzled g^(r&7),
// reads XOR (l15&7). T5 setprio around each MFMA cluster.
// Grid: 64 m-tiles x NT n-tiles, XCD-chunked: xcd = lin&7 owns an 8-mtile
// panel traversed n-fastest (A-panel ~2MB L2-resident per XCD).
// MODE 0: f32 out C[m*(NT*256)+n].
// MODE 2: n<2048 -> bf16 QK[m*2048+n]; n>=2048 -> VT[b,h,d,s] via LDS
//   transpose (pad-136 staging, coalesced 16B stores).
// ---------------------------------------------------------------------------
#define MMA8(BF, MH, NH)                                                                 \
  _Pragma("unroll") for (int mi = 0; mi < 2; ++mi)                                       \
  _Pragma("unroll") for (int ni = 0; ni < 2; ++ni)                                       \
  _Pragma("unroll") for (int ks = 0; ks < 2; ++ks)                                       \
      acc[(MH) * 2 + mi][(NH) * 2 + ni] =                                                \
          MFMA16(af[mi][ks], (BF)[ni][ks], acc[(MH) * 2 + mi][(NH) * 2 + ni]);

template <int MODE, int NT>
__global__ __launch_bounds__(512, 1) void gemm8(const bf16* __restrict__ A,
                                                const bf16* __restrict__ B,
                                                void* __restrict__ Cv,
                                                bf16* __restrict__ VT) {
  constexpr int K = 1024;
  __shared__ bf16 smem[49152];           // [A0 8K][A1 8K][B0 16K][B1 16K] elems, 96 KiB
  const int tid = threadIdx.x, lane = tid & 63, w = tid >> 6;
  const int l15 = lane & 15, l16 = lane >> 4;
  const int wr = w >> 2, wc = w & 3;     // wave grid 2(M) x 4(N)
  const int lin = blockIdx.x;
  const int idx = lin >> 3;
  const int mt = (lin & 7) * 8 + idx / NT;   // 64 m-tiles: 8 per XCD
  const int nt = idx % NT;
  const int bm0 = mt * 128, bn0 = nt * 256;

  auto stA = [&](int buf, int t, int j) {  // j=0,1: 8KB half of A-tile (128x64)
    const int r = j * 64 + (tid >> 3);
    const int g = (tid & 7) ^ (r & 7);
    GLOAD_LDS16(&A[(size_t)(bm0 + r) * K + t * 64 + g * 8],
                &smem[buf * 8192 + j * 4096 + tid * 8]);
  };
  auto stB = [&](int buf, int t, int j) {  // j=0..3: 8KB quarter of B-tile (256x64)
    const int r = j * 64 + (tid >> 3);
    const int g = (tid & 7) ^ (r & 7);
    GLOAD_LDS16(&B[(size_t)(bn0 + r) * K + t * 64 + g * 8],
                &smem[16384 + buf * 16384 + j * 4096 + tid * 8]);
  };
  bf16x8 af[2][2], b0[2][2], b1[2][2];
  auto ldA = [&](int buf, int mh, bf16x8 (&dst)[2][2]) {
#pragma unroll
    for (int mi = 0; mi < 2; ++mi)
#pragma unroll
      for (int ks = 0; ks < 2; ++ks)
        dst[mi][ks] = *reinterpret_cast<const bf16x8*>(
            &smem[buf * 8192 + (wr * 64 + mh * 32 + mi * 16 + l15) * 64 +
                  (((ks * 4 + l16) ^ (l15 & 7)) * 8)]);
  };
  auto ldB = [&](int buf, int nh, bf16x8 (&dst)[2][2]) {
#pragma unroll
    for (int ni = 0; ni < 2; ++ni)
#pragma unroll
      for (int ks = 0; ks < 2; ++ks)
        dst[ni][ks] = *reinterpret_cast<const bf16x8*>(
            &smem[16384 + buf * 16384 + (wc * 64 + nh * 32 + ni * 16 + l15) * 64 +
                  (((ks * 4 + l16) ^ (l15 & 7)) * 8)]);
  };

  f32x4 acc[4][4] = {};

  // prologue: tile0 -> buf0, tile1 -> buf1; certify tile0
  stA(0, 0, 0); stA(0, 0, 1);
  stB(0, 0, 0); stB(0, 0, 1); stB(0, 0, 2); stB(0, 0, 3);
  stA(1, 1, 0); stA(1, 1, 1);
  stB(1, 1, 0); stB(1, 1, 1); stB(1, 1, 2); stB(1, 1, 3);
  VMC(6); BAR();

#pragma unroll 1
  for (int it = 0; it < K / 128; ++it) {
    const int t0 = 2 * it;
    const bool last = (it == K / 128 - 1);
    // ph1: buf0 quad(0,0)
    ldA(0, 0, af); ldB(0, 0, b0);
    BAR(); LGKM0();
    PRIO1(); MMA8(b0, 0, 0); PRIO0();
    BAR();
    // ph2: quad(0,1)
    ldB(0, 1, b1);
    BAR(); LGKM0();
    PRIO1(); MMA8(b1, 0, 1); PRIO0();
    BAR();
    // ph3: quad(1,1)  (last buf0 ds_read)
    ldA(0, 1, af);
    BAR(); LGKM0();
    PRIO1(); MMA8(b1, 1, 1); PRIO0();
    BAR();
    // ph4: quad(1,0); stage tile t0+2 -> buf0 (freed by ph3 barrier); gate buf1
    if (!last) {
      stA(0, t0 + 2, 0); stA(0, t0 + 2, 1);
      stB(0, t0 + 2, 0); stB(0, t0 + 2, 1); stB(0, t0 + 2, 2); stB(0, t0 + 2, 3);
    }
    PRIO1(); MMA8(b0, 1, 0); PRIO0();
    if (last) { VMC(0); } else { VMC(6); }
    BAR();
    // ph5: buf1 quad(0,0)
    ldA(1, 0, af); ldB(1, 0, b0);
    BAR(); LGKM0();
    PRIO1(); MMA8(b0, 0, 0); PRIO0();
    BAR();
    // ph6: quad(0,1)
    ldB(1, 1, b1);
    BAR(); LGKM0();
    PRIO1(); MMA8(b1, 0, 1); PRIO0();
    BAR();
    // ph7: quad(1,1)  (last buf1 ds_read)
    ldA(1, 1, af);
    BAR(); LGKM0();
    PRIO1(); MMA8(b1, 1, 1); PRIO0();
    BAR();
    // ph8: quad(1,0); stage tile t0+3 -> buf1; gate buf0
    if (!last) {
      stA(1, t0 + 3, 0); stA(1, t0 + 3, 1);
      stB(1, t0 + 3, 0); stB(1, t0 + 3, 1); stB(1, t0 + 3, 2); stB(1, t0 + 3, 3);
    }
    PRIO1(); MMA8(b0, 1, 0); PRIO0();
    if (!last) VMC(6);
    BAR();
  }

  // epilogue. elem (i,j,r): row = bm0 + wr*64 + (i>>1)*32 + (i&1)*16 + l16*4 + r
  //                        col = bn0 + wc*64 + (j>>1)*32 + (j&1)*16 + l15
  if constexpr (MODE == 0) {
#pragma unroll
    for (int i = 0; i < 4; ++i)
#pragma unroll
      for (int j = 0; j < 4; ++j)
#pragma unroll
        for (int r = 0; r < 4; ++r) {
          const size_t row = bm0 + wr * 64 + (i >> 1) * 32 + (i & 1) * 16 + l16 * 4 + r;
          const size_t col = bn0 + wc * 64 + (j >> 1) * 32 + (j & 1) * 16 + l15;
          reinterpret_cast<float*>(Cv)[row * (NT * 256) + col] = acc[i][j][r];
        }
  } else {
    if (bn0 < 2048) {
#pragma unroll
      for (int i = 0; i < 4; ++i)
#pragma unroll
        for (int j = 0; j < 4; ++j)
#pragma unroll
          for (int r = 0; r < 4; ++r) {
            const size_t row = bm0 + wr * 64 + (i >> 1) * 32 + (i & 1) * 16 + l16 * 4 + r;
            const size_t col = bn0 + wc * 64 + (j >> 1) * 32 + (j & 1) * 16 + l15;
            reinterpret_cast<bf16*>(Cv)[row * 2048 + col] = (bf16)acc[i][j][r];
          }
    } else {
      // VT tile: transpose 128(m) x 256(n) through LDS (stride 136: 2-way banks)
#pragma unroll
      for (int i = 0; i < 4; ++i)
#pragma unroll
        for (int j = 0; j < 4; ++j)
#pragma unroll
          for (int r = 0; r < 4; ++r) {
            const int m = wr * 64 + (i >> 1) * 32 + (i & 1) * 16 + l16 * 4 + r;
            const int n = wc * 64 + (j >> 1) * 32 + (j & 1) * 16 + l15;
            smem[n * 136 + m] = (bf16)acc[i][j][r];
          }
      BAR();
      // store: thread -> (n = tid>>1, half = tid&1), 64 contiguous m each
      const int n = tid >> 1, half = tid & 1;
      const size_t vbase = ((size_t)(bm0 >> 11) * 1024 + (bn0 - 2048 + n)) * 2048 +
                           (bm0 & 2047) + half * 64;
#pragma unroll
      for (int k = 0; k < 8; ++k) {
        bf16x8 v = *reinterpret_cast<const bf16x8*>(&smem[n * 136 + half * 64 + k * 8]);
        *reinterpret_cast<bf16x8*>(&VT[vbase + k * 8]) = v;
      }
    }
  }
}

// ---------------------------------------------------------------------------
// Causal attention (unchanged from R6): no max subtraction, faithful softmax.
// QK packed [B,S,2048]: Q cols h*64, K cols 1024+h*64. VT [b,h,d(64),s(2048)].
// T3-min pipeline: stage(t+1) before compute(t), dbuf K/V, one vmcnt0+bar/tile.
// ---------------------------------------------------------------------------
constexpr int S_ = 2048, H_ = 16, LDQK = 2048;

__global__ __launch_bounds__(256) void attn_kernel(const bf16* __restrict__ QK,
                                                   const bf16* __restrict__ VT,
                                                   bf16* __restrict__ AO) {
  __shared__ bf16 Ks[2][64 * 64];      // K tile  [kv][hd]  swizzled, dbuf  16 KB
  __shared__ bf16 Vs[2][64 * 64];      // V^T tile [hd][kv] swizzled, dbuf  16 KB
  __shared__ bf16 Ps[4][32 * 64];      // per-wave P [q][kv] swizzled       16 KB
  const int tid = threadIdx.x, lane = tid & 63, w = tid >> 6;
  const int l15 = lane & 15, l16 = lane >> 4;
  const int bh = blockIdx.x, b = bh >> 4, h = bh & (H_ - 1);
  const int qy = blockIdx.y;
  const int qt = qy ^ (((qy >> 2) & 1) * 3);   // load-balance remap (bijective)
  const int q0 = qt * 128;
  const size_t qoff = (size_t)b * S_ * LDQK + h * 64;
  const size_t koff = qoff + 1024;
  const size_t voff = (size_t)bh * 64 * LDQK;  // VT row stride 2048
  const int qrow = q0 + w * 32;
  const int tmax = (qrow + 31) >> 6;           // this wave's diagonal tile

  auto stage = [&](int t) {
    const int kv0 = t * 64, bs = t & 1;
#pragma unroll
    for (int i = 0; i < 2; ++i) {
      const int c = tid + 256 * i;
      const int row = c >> 3, gs = (c & 7) ^ (row & 7);
      GLOAD_LDS16(&QK[koff + (size_t)(kv0 + row) * LDQK + gs * 8], &Ks[bs][c * 8]);
      GLOAD_LDS16(&VT[voff + (size_t)row * LDQK + kv0 + gs * 8], &Vs[bs][c * 8]);
    }
  };

  bf16x8 qf[2][2];
#pragma unroll
  for (int mi = 0; mi < 2; ++mi)
#pragma unroll
    for (int kk = 0; kk < 2; ++kk)
      qf[mi][kk] = *reinterpret_cast<const bf16x8*>(
          &QK[qoff + (size_t)(qrow + mi * 16 + l15) * LDQK + kk * 32 + l16 * 8]);

  f32x4 o[2][4] = {};
  float rs[2][4] = {};
  const int ntiles = 2 * qt + 2;

  stage(0);
  VMC(0); BAR();

  for (int t = 0; t < ntiles; ++t) {
    if (t + 1 < ntiles) stage(t + 1);          // issue-early: hides under compute
    if (t <= tmax) {                           // skip fully-masked tiles
      const int bs = t & 1;
      const int kv0 = t * 64;
      f32x4 sc[2][4] = {};
      bf16x8 kf[4][2];
#pragma unroll
      for (int ni = 0; ni < 4; ++ni)
#pragma unroll
        for (int kk = 0; kk < 2; ++kk)
          kf[ni][kk] = *reinterpret_cast<bf16x8*>(
              &Ks[bs][(ni * 16 + l15) * 64 + (((kk * 4 + l16) ^ (l15 & 7)) * 8)]);
#pragma unroll
      for (int mi = 0; mi < 2; ++mi)
#pragma unroll
        for (int ni = 0; ni < 4; ++ni)
#pragma unroll
          for (int kk = 0; kk < 2; ++kk)
            sc[mi][ni] = MFMA16(qf[mi][kk], kf[ni][kk], sc[mi][ni]);

      if (t == tmax) {
#pragma unroll
        for (int mi = 0; mi < 2; ++mi)
#pragma unroll
          for (int ni = 0; ni < 4; ++ni)
#pragma unroll
            for (int r = 0; r < 4; ++r) {
              const int lrow = mi * 16 + l16 * 4 + r;
              const int lcol = ni * 16 + l15;
              float p = (kv0 + lcol <= qrow + lrow) ? __expf(sc[mi][ni][r] * 0.125f) : 0.0f;
              rs[mi][r] += p;
              Ps[w][lrow * 64 + (lcol ^ ((lrow & 7) << 3))] = (bf16)p;
            }
      } else {
#pragma unroll
        for (int mi = 0; mi < 2; ++mi)
#pragma unroll
          for (int ni = 0; ni < 4; ++ni)
#pragma unroll
            for (int r = 0; r < 4; ++r) {
              const int lrow = mi * 16 + l16 * 4 + r;
              const int lcol = ni * 16 + l15;
              float p = __expf(sc[mi][ni][r] * 0.125f);
              rs[mi][r] += p;
              Ps[w][lrow * 64 + (lcol ^ ((lrow & 7) << 3))] = (bf16)p;
            }
      }

      bf16x8 pf[2][2], vf[4][2];
#pragma unroll
      for (int mi = 0; mi < 2; ++mi)
#pragma unroll
        for (int kk = 0; kk < 2; ++kk)
          pf[mi][kk] = *reinterpret_cast<bf16x8*>(
              &Ps[w][(mi * 16 + l15) * 64 + (((kk * 4 + l16) ^ (l15 & 7)) * 8)]);
#pragma unroll
      for (int ni = 0; ni < 4; ++ni)
#pragma unroll
        for (int kk = 0; kk < 2; ++kk)
          vf[ni][kk] = *reinterpret_cast<bf16x8*>(
              &Vs[bs][(ni * 16 + l15) * 64 + (((kk * 4 + l16) ^ (l15 & 7)) * 8)]);
#pragma unroll
      for (int mi = 0; mi < 2; ++mi)
#pragma unroll
        for (int ni = 0; ni < 4; ++ni)
#pragma unroll
          for (int kk = 0; kk < 2; ++kk)
            o[mi][ni] = MFMA16(pf[mi][kk], vf[ni][kk], o[mi][ni]);
    }
    VMC(0); BAR();   // t+1's loads landed (issued before compute -> ~free wait)
  }

#pragma unroll
  for (int mi = 0; mi < 2; ++mi)
#pragma unroll
    for (int r = 0; r < 4; ++r) {
      float v = rs[mi][r];
      v += __shfl_xor(v, 1);
      v += __shfl_xor(v, 2);
      v += __shfl_xor(v, 4);
      v += __shfl_xor(v, 8);
      rs[mi][r] = v + 1e-10f;
    }

  const size_t aoff = (size_t)b * S_ * 1024 + h * 64;
#pragma unroll
  for (int mi = 0; mi < 2; ++mi)
#pragma unroll
    for (int ni = 0; ni < 4; ++ni)
#pragma unroll
      for (int r = 0; r < 4; ++r) {
        int row = qrow + mi * 16 + l16 * 4 + r;
        AO[aoff + (size_t)row * 1024 + ni * 16 + l15] = (bf16)(o[mi][ni][r] / rs[mi][r]);
      }
}

// ---------------------------------------------------------------------------
extern "C" void kernel_launch(void* const* d_in, const int* in_sizes, int n_in,
                              void* d_out, int out_size, void* d_ws, size_t ws_size,
                              hipStream_t stream) {
  const float* x  = (const float*)d_in[0];
  // d_in[1] = mask: exactly causal additive -1e9; handled analytically, unused.
  const float* Wq = (const float*)d_in[2];
  const float* Wk = (const float*)d_in[3];
  const float* Wv = (const float*)d_in[4];
  const float* Wo = (const float*)d_in[5];

  constexpr int B = 4, S = 2048, D = 1024;
  constexpr size_t nx = (size_t)B * S * D;       // 8,388,608
  constexpr size_t nw = (size_t)D * D;           // 1,048,576

  char* ws = (char*)d_ws;
  bf16* xb    = (bf16*)ws;                   // x bf16                (16.78 MB)
  bf16* Wqkvb = xb + nx;                     // packed [3072][1024]   ( 6.29 MB)
  bf16* Wob   = Wqkvb + 3 * nw;              // Wo bf16               ( 2.10 MB)
  bf16* QKb   = Wob + nw;                    // QK [B,S,2048]         (33.55 MB)
  bf16* VTb   = QKb + (size_t)B * S * 2048;  // V^T [b,h,64,2048]     (16.78 MB)
  bf16* AOb   = VTb + nx;                    // attn out [B,S,D]      (16.78 MB)

  cvt_all<<<2048, 256, 0, stream>>>(x, Wq, Wk, Wv, Wo, xb, Wqkvb, Wob);

  // fused QKV projection, 8-phase 128x256 tiles, 768 blocks (3 exact rounds)
  gemm8<2, 12><<<768, 512, 0, stream>>>(xb, Wqkvb, QKb, VTb);

  attn_kernel<<<dim3(B * H_, S / 128), 256, 0, stream>>>(QKb, VTb, AOb);

  // output projection, 256 blocks (1 exact round) -> f32 d_out
  gemm8<0, 4><<<256, 512, 0, stream>>>(AOb, Wob, d_out, nullptr);
}